// Round 1
// baseline (126.601 us; speedup 1.0000x reference)
//
#include <hip/hip_runtime.h>

// LengthRegulator: B=32, T=256, D=384, MAX_LEN=2048
// out[b,f,:] = x[b, searchsorted(csum[b], f, 'right'), :] if f < mel_len[b] else 0
// mel_len[b] = csum[b, T-1]
//
// v2: kernel 1 scatters the frame->token index table directly (no per-block
// binary search in expand); expand does 32 frames/block (48 KiB of stores per
// 128 B preamble) with a uniform fast path for fully-invalid tiles.

#define BB 32
#define TT 256
#define DD 384
#define MAXLEN 2048
#define D4 (DD / 4)            // 96 float4 per frame
#define FPB 32                 // frames per expand block
#define TILES (MAXLEN / FPB)   // 64 tiles per batch

__global__ __launch_bounds__(256) void scan_scatter_kernel(const int* __restrict__ duration,
                                                           int* __restrict__ idx_tbl,
                                                           float* __restrict__ mel_out) {
    __shared__ int s[TT];
    const int b = blockIdx.x;
    const int t = threadIdx.x;
    const int d = duration[b * TT + t];
    s[t] = d;
    __syncthreads();
    // Hillis-Steele inclusive scan over 256 elements
    for (int off = 1; off < TT; off <<= 1) {
        int cur = s[t];
        int add = (t >= off) ? s[t - off] : 0;
        __syncthreads();
        s[t] = cur + add;
        __syncthreads();
    }
    const int end = s[t];          // csum[b, t] (inclusive)
    const int mel = s[TT - 1];     // total frames for this batch
    int* __restrict__ row = idx_tbl + b * MAXLEN;
    // Token t owns frames [end-d, end); searchsorted(side='right') == t there.
    for (int f = end - d; f < end; ++f) row[f] = t;
    // Invalid tail [mel, MAXLEN) -> -1 (cooperative strided fill)
    for (int f = mel + t; f < MAXLEN; f += TT) row[f] = -1;
    if (t == TT - 1) {
        // Output buffer is fp32; mel_len written as float value.
        mel_out[b] = (float)end;
    }
}

__global__ __launch_bounds__(256) void expand_kernel(const float* __restrict__ x,
                                                     const int* __restrict__ idx_tbl,
                                                     float* __restrict__ out) {
    __shared__ int s_idx[FPB];

    const int bid = blockIdx.x;
    const int b = bid >> 6;            // bid / TILES (TILES == 64)
    const int tile = bid & (TILES - 1);
    const int tid = threadIdx.x;

    if (tid < FPB) {
        s_idx[tid] = idx_tbl[b * MAXLEN + tile * FPB + tid];
    }
    __syncthreads();

    float4* __restrict__ o4 = (float4*)(out + ((size_t)b * MAXLEN + (size_t)tile * FPB) * DD);

    // idx is monotone along frames: if the first frame of the tile is invalid,
    // the whole tile is invalid -> pure zero-store stream (no x/LDS reads).
    if (s_idx[0] < 0) {
        const float4 z = make_float4(0.f, 0.f, 0.f, 0.f);
        #pragma unroll
        for (int i = 0; i < (FPB * D4) / 256; ++i) {
            o4[i * 256 + tid] = z;
        }
        return;
    }

    const float4* __restrict__ x4 = (const float4*)(x + (size_t)b * TT * DD);

    // FPB * D4 = 3072 float4 per tile; 256 threads -> 12 fully-coalesced,
    // fully-unrolled iterations (12 independent loads in flight).
    #pragma unroll
    for (int i = 0; i < (FPB * D4) / 256; ++i) {
        const int g = i * 256 + tid;
        const int fl = g / D4;          // frame within tile (0..31), const-divide -> magic mul
        const int vv = g - fl * D4;     // float4 column (0..95)
        const int idx = s_idx[fl];
        float4 val = make_float4(0.f, 0.f, 0.f, 0.f);
        if (idx >= 0) {
            val = x4[(size_t)idx * D4 + vv];
        }
        o4[g] = val;                    // contiguous across the whole tile
    }
}

extern "C" void kernel_launch(void* const* d_in, const int* in_sizes, int n_in,
                              void* d_out, int out_size, void* d_ws, size_t ws_size,
                              hipStream_t stream) {
    const float* x = (const float*)d_in[0];
    const int* duration = (const int*)d_in[1];
    // d_in[2] = max_len (known constant 2048)

    float* out = (float*)d_out;                       // [B, MAXLEN, D] fp32
    float* mel_out = out + (size_t)BB * MAXLEN * DD;  // [B] mel_len, as float values
    int* idx_tbl = (int*)d_ws;                        // [B, MAXLEN] frame->token index

    scan_scatter_kernel<<<BB, TT, 0, stream>>>(duration, idx_tbl, mel_out);
    expand_kernel<<<BB * TILES, 256, 0, stream>>>(x, idx_tbl, out);
}